// Round 7
// baseline (559.365 us; speedup 1.0000x reference)
//
#include <hip/hip_runtime.h>
#include <hip/hip_bf16.h>
#include <stdint.h>

// B=512, N=256, D=128, 4 layers. One block (512 thr, 8 waves) per batch.
// Wave w owns rows {16w..16w+15} and {16w+128..16w+143}. f32 master Z in
// registers (Zf[2][8][4], MFMA D-frag layout). acc lives in GLOBAL memory
// (streamed bf16-packed, coalesced), carved out of this block's own d_out
// slice (first 64 KB of 129.5 KB; final-layer output overwrites it after the
// last acc read). Col-128 master in LDS zbar (f32); row-256 distributed.
// Per layer:
//   K: keyT[i][tok] = (Z P^T)^T (bf16, token-contiguous) + W256 row
//   M: W = Z Q -> per col-half {S^T = Z W^T -> R-half -> fused Z/acc update}
//   C: post-barrier commit: Zbf/zbar from f32 master, row-256, Zo on layer 3
// R7 rationale: R3-R6 all spilled ~32-50 regs (450 MB HBM scratch traffic,
// MfmaUtil 7.4%). Persistent acc (32 regs) -> global; racc halved 32->16 by
// computing R in column halves (S^T runs twice; MFMA issue is cheap).
// Peak live ~126 fits the 128-VGPR budget the compiler insists on.

using short8 = __attribute__((ext_vector_type(8))) short;
using f32x4  = __attribute__((ext_vector_type(4))) float;

#define MFMA16(A,B,C) __builtin_amdgcn_mfma_f32_16x16x32_bf16((A),(B),(C),0,0,0)

__device__ __forceinline__ uint16_t f2bf(float f) {
  union { __hip_bfloat16 h; uint16_t u; } cv; cv.h = __float2bfloat16(f); return cv.u;
}
__device__ __forceinline__ uint32_t pk2(float lo, float hi) {
  return (uint32_t)f2bf(lo) | ((uint32_t)f2bf(hi) << 16);
}
__device__ __forceinline__ float bflo(uint32_t p) { return __uint_as_float(p << 16); }
__device__ __forceinline__ float bfhi(uint32_t p) { return __uint_as_float(p & 0xffff0000u); }

// ---- LDS geometry (bytes); all tile row strides are multiples of 16 B ----
#define ZP        136                      // Zbf pitch elems (272 B rows)
#define KP        264                      // keyT pitch elems (528 B rows)
#define ZB_OFF    0
#define KT_OFF    (257*ZP*2)               // 69,904
#define ZBAR_OFF  (KT_OFF + 128*KP*2)      // 137,488
#define ZF256_OFF (ZBAR_OFF + 1040)        // 138,528
#define A256_OFF  (ZF256_OFF + 528)        // 139,056
#define W256_OFF  (A256_OFF + 528)         // 139,584
#define S256_OFF  (W256_OFF + 256)         // 139,840
#define P128_OFF  (S256_OFF + 512)         // 140,352
#define SCR_OFF   (P128_OFF + 64)          // 140,416
#define SCRP      40                       // scratch pitch elems (80 B rows)
#define LDS_TOTAL (SCR_OFF + 8*16*SCRP*2)  // 150,656 <= 163,840

__global__ __launch_bounds__(512)
__attribute__((amdgpu_waves_per_eu(2)))
void tf_layers(const float* __restrict__ Zin, const float* __restrict__ gamma,
               const uint16_t* __restrict__ Qtg, const uint16_t* __restrict__ Pg,
               float* __restrict__ Zout)
{
  extern __shared__ char lds[];
  uint16_t* Zbf   = (uint16_t*)(lds + ZB_OFF);   // [257][ZP] bf16, cols<128
  uint16_t* keyT  = (uint16_t*)(lds + KT_OFF);   // [128][KP] bf16, keyT[i][tok]
  float*    zbar  = (float*)(lds + ZBAR_OFF);    // [257] f32 master col 128
  float*    Zf256 = (float*)(lds + ZF256_OFF);   // [128] f32 master row 256
  float*    acc256= (float*)(lds + A256_OFF);    // [129] f32 acc row 256
  uint16_t* W256  = (uint16_t*)(lds + W256_OFF); // [128] bf16
  uint16_t* S256  = (uint16_t*)(lds + S256_OFF); // [256] bf16
  float*    p128  = (float*)(lds + P128_OFF);    // [8]   f32 partials

  const int tid = threadIdx.x, lane = tid & 63, w = tid >> 6;   // w: 0..7
  const int l15 = lane & 15, g = lane >> 4;
  const int b = blockIdx.x;
  const float inv_n = 1.0f/256.0f;

  uint16_t* scr = (uint16_t*)(lds + SCR_OFF) + w * 16 * SCRP;  // per-wave [16][SCRP]

  const float* Zb = Zin + (size_t)b*33153;   // 257*129
  float*       Zo = Zout + (size_t)b*33153;

  // acc scratch: 16B-aligned region inside this block's own output slice.
  // 8 uint4 slots/thread: slot(ti,h,j) = ((ti*2+h)*2+j)*512 + tid  -> 64 KB.
  uint4* accb = (uint4*)(((uintptr_t)Zo + 15) & ~(uintptr_t)15);

  // ---- init ----
  for (int i2 = tid; i2 < 33153; i2 += 512) {
    int r = i2/129, c = i2 - r*129;
    float v = Zb[i2];
    if (c < 128) Zbf[r*ZP + c] = f2bf(v); else zbar[r] = v;
  }
  if (tid < 128) Zf256[tid] = Zb[256*129 + tid];
  if (tid <= 128) acc256[tid] = 0.0f;

  // f32 master rows (D-frag layout: row mb+4g+r, col 16it+l15), 2 tiles
  float Zf[2][8][4];
#pragma unroll
  for (int ti = 0; ti < 2; ++ti) {
    const int mb = 16*w + 128*ti;
#pragma unroll
    for (int it = 0; it < 8; ++it)
#pragma unroll
      for (int r = 0; r < 4; ++r)
        Zf[ti][it][r] = Zb[(mb + 4*g + r)*129 + 16*it + l15];
  }

  float a128[2] = {0.0f, 0.0f};
  float r128v[2];

#pragma unroll 1
  for (int l = 0; l < 4; ++l) {
    const uint16_t* Ql  = Qtg + l*16384;
    const uint16_t* Pl  = Pg  + l*16384;
    const float*    gml = gamma + l*33153;
    const bool last = (l == 3);

    __syncthreads();   // Zbf/zbar/Zf256 stable (init or previous commit)

    // ===== K: keyT[i][tok] = sum_d Z[tok][d] P[i][d]; + W256 row =====
    {
      const int irow = 16*w + l15;     // i-tile w (8 tiles cover 128 rows)
      short8 bk[4];
#pragma unroll
      for (int kk = 0; kk < 4; ++kk)
        bk[kk] = *(const short8*)(Pl + irow*128 + kk*32 + g*8);
#pragma unroll
      for (int t = 0; t < 16; ++t) {
        f32x4 a4 = {0,0,0,0};
#pragma unroll
        for (int kk = 0; kk < 4; ++kk) {
          short8 az = *(const short8*)(Zbf + (16*t + l15)*ZP + kk*32 + g*8);
          a4 = MFMA16(az, bk[kk], a4);
        }
        uint32_t* dst = (uint32_t*)(keyT + irow*KP + 16*t + 4*g);
        dst[0] = pk2(a4[0], a4[1]); dst[1] = pk2(a4[2], a4[3]);
      }
      // W256[d] = dot(Qt[d], Z[256][:]) — 16 d per wave, 4 lanes per d
      {
        const int d = 16*w + (lane >> 2), ks = (lane & 3)*32;
        const uint32_t* qr = (const uint32_t*)(Ql + d*128 + ks);
        const uint32_t* zr = (const uint32_t*)(Zbf + 256*ZP + ks);
        float v = 0;
#pragma unroll
        for (int j = 0; j < 16; ++j) {
          uint32_t q_ = qr[j], z_ = zr[j];
          v += bflo(q_)*bflo(z_) + bfhi(q_)*bfhi(z_);
        }
        v += __shfl_xor(v,1); v += __shfl_xor(v,2);
        if ((lane & 3) == 0) W256[d] = f2bf(v);
      }
    }
    __syncthreads();   // keyT + W256 ready

    // ===== M: per tile: W -> per col-half {S^T -> R -> fused Z/acc} =====
    float pacc = 0.0f;
#pragma unroll
    for (int ti = 0; ti < 2; ++ti) {
      const int mb = 16*w + 128*ti;

      // S256[tok] for 16 toks of this tile (4 lanes per tok)
      {
        const int tok = mb + (lane >> 2), ds0 = (lane & 3)*32;
        const uint32_t* wr = (const uint32_t*)(W256 + ds0);
        const uint32_t* zr = (const uint32_t*)(Zbf + tok*ZP + ds0);
        float v = 0;
#pragma unroll
        for (int j2 = 0; j2 < 16; ++j2) {
          uint32_t a_ = wr[j2], z_ = zr[j2];
          v += bflo(a_)*bflo(z_) + bfhi(a_)*bfhi(z_);
        }
        v += __shfl_xor(v,1); v += __shfl_xor(v,2);
        if ((lane & 3) == 0) { S256[tok] = f2bf(v); pacc += v * zbar[tok]; }
      }

      // W[m][d] = sum_k Z[m][k] Qt[d][k]: 4 chunks of 32 d, scratch relayout
      short8 bw[4];
      {
        short8 bz[4];
#pragma unroll
        for (int kk = 0; kk < 4; ++kk)
          bz[kk] = *(const short8*)(Zbf + (mb + l15)*ZP + kk*32 + g*8);
#pragma unroll
        for (int q32 = 0; q32 < 4; ++q32) {
#pragma unroll
          for (int hf = 0; hf < 2; ++hf) {          // d-tile dt = 2*q32 + hf
            const int dt = 2*q32 + hf;
            f32x4 t4 = {0,0,0,0};
#pragma unroll
            for (int kk = 0; kk < 4; ++kk) {
              short8 aq = *(const short8*)(Ql + (16*dt + l15)*128 + kk*32 + g*8);
              t4 = MFMA16(aq, bz[kk], t4);
            }
            // D: col=m=l15, rows d = 16dt + 4g + r -> scr[m][16hf+4g+r]
            uint32_t* dst = (uint32_t*)(scr + l15*SCRP + 16*hf + 4*g);
            dst[0] = pk2(t4[0], t4[1]); dst[1] = pk2(t4[2], t4[3]);
          }
          bw[q32] = *(const short8*)(scr + l15*SCRP + g*8);  // same-wave RAW
        }
      }

      float rr = 0.0f;
#pragma unroll
      for (int h = 0; h < 2; ++h) {    // output col halves (it = 4h..4h+3)
        f32x4 racc[4];
#pragma unroll
        for (int i = 0; i < 4; ++i) racc[i] = (f32x4){0,0,0,0};
#pragma unroll
        for (int p = 0; p < 4; ++p) {  // token chunks of 64
          f32x4 sacc[4];
#pragma unroll
          for (int t = 0; t < 4; ++t) sacc[t] = (f32x4){0,0,0,0};
#pragma unroll
          for (int t = 0; t < 4; ++t)
#pragma unroll
            for (int q = 0; q < 4; ++q) {
              short8 az = *(const short8*)(Zbf + (64*p + 16*t + l15)*ZP + q*32 + g*8);
              sacc[t] = MFMA16(az, bw[q], sacc[t]);
            }
          if (h == 0) {                // GEMV vs zbar, once
#pragma unroll
            for (int t = 0; t < 4; ++t) {
              f32x4 z4 = *(const f32x4*)(zbar + 64*p + 16*t + 4*g);
              rr += sacc[t][0]*z4[0] + sacc[t][1]*z4[1]
                  + sacc[t][2]*z4[2] + sacc[t][3]*z4[3];
            }
          }
#pragma unroll
          for (int hf = 0; hf < 2; ++hf) {
#pragma unroll
            for (int tt = 0; tt < 2; ++tt) {
              f32x4 v = sacc[2*hf + tt];
              uint32_t* dst = (uint32_t*)(scr + l15*SCRP + 16*tt + 4*g);
              dst[0] = pk2(v[0], v[1]); dst[1] = pk2(v[2], v[3]);
            }
            short8 sA = *(const short8*)(scr + l15*SCRP + g*8);  // same-wave RAW
#pragma unroll
            for (int it2 = 0; it2 < 4; ++it2) {
              short8 bkey = *(const short8*)(keyT + (16*(4*h+it2) + l15)*KP + 64*p + 32*hf + 8*g);
              racc[it2] = MFMA16(sA, bkey, racc[it2]);
            }
          }
        }
        // fused Z/acc update for this col half
        uint32_t ao[8];
        if (l > 0) {
          uint4 q0 = accb[(((ti*2 + h)*2 + 0) << 9) + tid];
          uint4 q1 = accb[(((ti*2 + h)*2 + 1) << 9) + tid];
          ao[0]=q0.x; ao[1]=q0.y; ao[2]=q0.z; ao[3]=q0.w;
          ao[4]=q1.x; ao[5]=q1.y; ao[6]=q1.z; ao[7]=q1.w;
        } else {
#pragma unroll
          for (int i = 0; i < 8; ++i) ao[i] = 0;
        }
        uint32_t an[8];
#pragma unroll
        for (int it2 = 0; it2 < 4; ++it2) {
          const int it = 4*h + it2, col = 16*it + l15;
          float R0 = racc[it2][0]*inv_n, R1 = racc[it2][1]*inv_n;
          float R2 = racc[it2][2]*inv_n, R3 = racc[it2][3]*inv_n;
          float A0 = bflo(ao[2*it2]),   A1 = bfhi(ao[2*it2]);
          float A2 = bflo(ao[2*it2+1]), A3 = bfhi(ao[2*it2+1]);
          const float* gp = gml + (mb + 4*g)*129 + col;
          float An0, An1, An2, An3;
          Zf[ti][it][0] += R0 + A0; An0 = A0 + R0*gp[0];
          Zf[ti][it][1] += R1 + A1; An1 = A1 + R1*gp[129];
          Zf[ti][it][2] += R2 + A2; An2 = A2 + R2*gp[258];
          Zf[ti][it][3] += R3 + A3; An3 = A3 + R3*gp[387];
          an[2*it2]   = pk2(An0, An1);
          an[2*it2+1] = pk2(An2, An3);
        }
        if (!last) {
          accb[(((ti*2 + h)*2 + 0) << 9) + tid] = make_uint4(an[0],an[1],an[2],an[3]);
          accb[(((ti*2 + h)*2 + 1) << 9) + tid] = make_uint4(an[4],an[5],an[6],an[7]);
        }
      }
      rr += __shfl_xor(rr, 16);
      rr += __shfl_xor(rr, 32);
      r128v[ti] = rr * inv_n;
    }
    pacc += __shfl_xor(pacc,1);  pacc += __shfl_xor(pacc,2);
    pacc += __shfl_xor(pacc,4);  pacc += __shfl_xor(pacc,8);
    pacc += __shfl_xor(pacc,16); pacc += __shfl_xor(pacc,32);
    if (lane == 0) p128[w] = pacc;

    __syncthreads();   // all M reads of Zbf/zbar done; S256/p128 ready

    // ===== C: commit Zbf/zbar from f32 master; row 256; Zo on last =====
    {
#pragma unroll
      for (int ti = 0; ti < 2; ++ti) {
        const int mb = 16*w + 128*ti;
#pragma unroll
        for (int it = 0; it < 8; ++it) {
          const int col = 16*it + l15;
#pragma unroll
          for (int r = 0; r < 4; ++r) {
            const int m = mb + 4*g + r;
            float zf = Zf[ti][it][r];
            Zbf[m*ZP + col] = f2bf(zf);
            if (last) Zo[m*129 + col] = zf;
          }
        }
        if (lane < 16) {
          const int m = mb + l15;
          float zo = zbar[m], ga = gml[m*129 + 128];
          float zn = zo + r128v[ti] + a128[ti];
          zbar[m] = zn;
          a128[ti] = a128[ti] + r128v[ti]*ga;
          if (last) Zo[m*129 + 128] = zn;
        }
      }
      // row 256: R256[i] = dot(S256, keyT[i]) / n — 16 i per wave, 4 lanes/i
      {
        const int i = 16*w + (lane >> 2), ts0 = (lane & 3)*64;
        const uint32_t* sr = (const uint32_t*)(S256 + ts0);
        const uint32_t* kr = (const uint32_t*)(keyT + i*KP + ts0);
        float v = 0;
#pragma unroll
        for (int j2 = 0; j2 < 32; ++j2) {
          uint32_t s_ = sr[j2], k_ = kr[j2];
          v += bflo(s_)*bflo(k_) + bfhi(s_)*bfhi(k_);
        }
        v += __shfl_xor(v,1); v += __shfl_xor(v,2);
        if ((lane & 3) == 0) {
          float R = v*inv_n;
          float zo = Zf256[i], ao = acc256[i], ga = gml[256*129 + i];
          float zn = zo + R + ao;
          Zf256[i] = zn;
          acc256[i] = ao + R*ga;
          Zbf[256*ZP + i] = f2bf(zn);
          if (last) Zo[256*129 + i] = zn;
        }
        if (w == 7 && lane == 0) {
          float s = 0;
#pragma unroll
          for (int k = 0; k < 8; ++k) s += p128[k];
          float R = s*inv_n;
          float ga = gml[256*129 + 128];
          float zn = zbar[256] + R + acc256[128];
          zbar[256] = zn;
          acc256[128] = acc256[128] + R*ga;
          if (last) Zo[256*129 + 128] = zn;
        }
      }
    }
  }
}

// allparam f32 -> bf16: Pg[l][i][d] = P[i][d]; Qtg[l][d][k] = Q[k][d].
__global__ void prep_params(const float* __restrict__ ap,
                            uint16_t* __restrict__ qtg, uint16_t* __restrict__ pg)
{
  int t = blockIdx.x * 256 + threadIdx.x;   // 0..65535
  int l = t >> 14, rem = t & 16383, i = rem >> 7, j = rem & 127;
  pg[t]  = f2bf(ap[((l*2 + 0)*128 + i)*128 + j]);
  qtg[t] = f2bf(ap[((l*2 + 1)*128 + j)*128 + i]);
}

extern "C" void kernel_launch(void* const* d_in, const int* in_sizes, int n_in,
                              void* d_out, int out_size, void* d_ws, size_t ws_size,
                              hipStream_t stream)
{
  const float* Z  = (const float*)d_in[0];
  const float* ap = (const float*)d_in[1];
  const float* gm = (const float*)d_in[2];

  uint16_t* qtg = (uint16_t*)d_ws;            // 4*128*128 bf16
  uint16_t* pg  = qtg + 4*128*128;            // 4*128*128 bf16 (256 KiB total)

  (void)hipFuncSetAttribute((const void*)tf_layers,
                            hipFuncAttributeMaxDynamicSharedMemorySize, LDS_TOTAL);

  prep_params<<<256, 256, 0, stream>>>(ap, qtg, pg);
  tf_layers<<<512, 512, LDS_TOTAL, stream>>>(Z, gm, qtg, pg, (float*)d_out);
}

// Round 8
// 428.697 us; speedup vs baseline: 1.3048x; 1.3048x over previous
//
#include <hip/hip_runtime.h>
#include <hip/hip_bf16.h>
#include <stdint.h>

// B=512, N=256, D=128, 4 layers. One block (512 thr, 8 waves) per batch.
// ALGORITHM (associativity): R = Attn*key/n = Z * (Qf * G * Pf^T) / n where
//   G = Z^T A Z = sum_{m<256} z_m z_m^T   (129x129 symmetric; A kills token 256)
// so with padding structure:  Gbar = G[0:128,0:128], g = G[0:128,128]:
//   T1 = Gbar*P^T; M0 = Q*T1; m1 = Q*g;  R[:,c<128] = Zc*M0/n; R[:,128] = Zc*m1/n.
// The NxN score matrix never exists; per-wave MFMA volume halves vs R6.
// STATE: master Z = bf16-hi in LDS (ZT, TRANSPOSED [d][tok]) + bf16-lo residual
// in regs (own rows) -> ~2^-17 rel precision; acc in regs (bf16 pairs).
// Per-thread persistent = 64 regs, peak live ~114 -> fits the 128-VGPR budget
// (R3-R7: everything bigger spilled ~450 MB to HBM; this design removes it).
// Phases/layer: G(SYRK, wave i-tile=w) -> T1 (regs) -> Mc (scratch relayout)
// -> R+fused update (col halves) -> row-256 update.  5 barriers/layer.

using short8 = __attribute__((ext_vector_type(8))) short;
using f32x4  = __attribute__((ext_vector_type(4))) float;

#define MFMA16(A,B,C) __builtin_amdgcn_mfma_f32_16x16x32_bf16((A),(B),(C),0,0,0)

static __device__ __forceinline__ uint16_t f2bf(float f){
  union{__hip_bfloat16 h;uint16_t u;}c; c.h=__float2bfloat16(f); return c.u; }
static __device__ __forceinline__ uint32_t pk2(float lo,float hi){
  return (uint32_t)f2bf(lo) | ((uint32_t)f2bf(hi)<<16); }
static __device__ __forceinline__ float bfu(uint16_t u){ return __uint_as_float(((uint32_t)u)<<16); }
static __device__ __forceinline__ float bflo(uint32_t p){ return __uint_as_float(p<<16); }
static __device__ __forceinline__ float bfhi(uint32_t p){ return __uint_as_float(p&0xffff0000u); }

union F4 { uint32_t u[4]; short8 s8; };

// ---- LDS geometry ---- (pitches chosen: 16B-aligned rows, <=2-way banks)
#define ZTP   280                           // ZT pitch (u16): [128][280], cols 0..256 used
#define BUFP  136                           // Gbar/Mc pitch (u16): [128][136]
#define SCRP  40                            // per-wave scratch pitch (u16): [16][40]
#define ZT_OFF   0                          // 128*280*2 = 71,680
#define BUF_OFF  71680                      // 128*136*2 = 34,816
#define SCR_OFF  106496                     // 8*16*40*2 = 10,240
#define ZBAR_OFF 116736                     // 260*4     =  1,040
#define Z256_OFF 117776                     // 128*4     =    512
#define A128_OFF 118288                     // 256*4     =  1,024
#define A256_OFF 119312                     // 132*4     =    528
#define G_OFF    119840                     // 128*4     =    512
#define M1_OFF   120352                     // 128*4     =    512
#define LDS_TOTAL 120864

__global__ __launch_bounds__(512)
__attribute__((amdgpu_waves_per_eu(2, 2)))
void tf_layers(const float* __restrict__ Zin, const float* __restrict__ gamma,
               const uint16_t* __restrict__ Qg, const uint16_t* __restrict__ Pg,
               float* __restrict__ Zout)
{
  extern __shared__ char lds[];
  uint16_t* ZT    = (uint16_t*)(lds + ZT_OFF);   // [128][ZTP]: ZT[d][tok]=bf16 Z[tok][d]
  uint16_t* Gb    = (uint16_t*)(lds + BUF_OFF);  // [128][BUFP]: Gbar, then Mc[c][d]
  float*    zbar  = (float*)(lds + ZBAR_OFF);    // [257] f32 master col 128
  float*    z256f = (float*)(lds + Z256_OFF);    // [128] f32 master row 256 (d<128)
  float*    acc128= (float*)(lds + A128_OFF);    // [256] f32 acc col 128
  float*    acc256= (float*)(lds + A256_OFF);    // [129] f32 acc row 256
  float*    gv    = (float*)(lds + G_OFF);       // [128] g = Gbar[:,128]
  float*    m1v   = (float*)(lds + M1_OFF);      // [128] m1 = Q*g

  const int tid = threadIdx.x, lane = tid & 63, w = tid >> 6;
  const int l15 = lane & 15, g4 = lane >> 4;
  const int b = blockIdx.x;
  const float inv_n = 1.0f/256.0f;

  uint16_t* scr = (uint16_t*)(lds + SCR_OFF) + w * 16 * SCRP;

  const float* Zb = Zin + (size_t)b*33153;   // 257*129
  float*       Zo = Zout + (size_t)b*33153;

  // ---- init: ZT (transposed bf16 hi), zbar, z256f, acc arrays ----
  for (int i2 = tid; i2 < 33153; i2 += 512) {
    int r = i2/129, c = i2 - r*129;
    float v = Zb[i2];
    if (c < 128) { ZT[c*ZTP + r] = f2bf(v); if (r == 256) z256f[c] = v; }
    else zbar[r] = v;
  }
  if (tid < 256) acc128[tid] = 0.0f;
  if (tid < 129) acc256[tid] = 0.0f;

  // lo residual + acc regs for own rows (D-frag layout: row mb+4g4+r, col 16it+l15)
  uint32_t lopk[2][16], apk[2][16];
#pragma unroll
  for (int ti = 0; ti < 2; ++ti) {
    const int mb = 16*w + 128*ti;
#pragma unroll
    for (int it = 0; it < 8; ++it) {
      const float* zp = Zb + (size_t)(mb + 4*g4)*129 + 16*it + l15;
      float v0 = zp[0], v1 = zp[129], v2 = zp[258], v3 = zp[387];
      lopk[ti][2*it]   = pk2(v0 - bfu(f2bf(v0)), v1 - bfu(f2bf(v1)));
      lopk[ti][2*it+1] = pk2(v2 - bfu(f2bf(v2)), v3 - bfu(f2bf(v3)));
      apk[ti][2*it] = 0; apk[ti][2*it+1] = 0;
    }
  }

#pragma unroll 1
  for (int l = 0; l < 4; ++l) {
    const uint16_t* Ql  = Qg + l*16384;
    const uint16_t* Pl  = Pg + l*16384;
    const float*    gml = gamma + l*33153;
    const bool last = (l == 3);

    __syncthreads();   // bar A: ZT/zbar/z256f stable; Buf free

    // ===== G: Gbar[i][j] = sum_{m<256} Z[m][i]Z[m][j]; g[i] = sum Z[m][i]zbar[m]
    {
      f32x4 gacc[8];
#pragma unroll
      for (int jt = 0; jt < 8; ++jt) gacc[jt] = (f32x4){0,0,0,0};
#pragma unroll
      for (int mw = 0; mw < 8; ++mw) {
        short8 af = *(const short8*)(ZT + (16*w+l15)*ZTP + 32*mw + 8*g4);
#pragma unroll
        for (int jt = 0; jt < 8; ++jt) {
          short8 bf = *(const short8*)(ZT + (16*jt+l15)*ZTP + 32*mw + 8*g4);
          gacc[jt] = MFMA16(af, bf, gacc[jt]);
        }
      }
      // symmetric write: lane holds G[i=16w+4g4+rr][j=16jt+l15] -> Gb[j][i]
#pragma unroll
      for (int jt = 0; jt < 8; ++jt)
        *(uint2*)(Gb + (16*jt+l15)*BUFP + 16*w + 4*g4) =
            make_uint2(pk2(gacc[jt][0],gacc[jt][1]), pk2(gacc[jt][2],gacc[jt][3]));
      // g GEMV: i = tid>>2, 4 lanes x 64 tokens
      {
        const int i = tid >> 2, q = lane & 3;
        const uint16_t* zr = ZT + i*ZTP + 64*q;
        float s = 0;
#pragma unroll
        for (int j = 0; j < 16; ++j) {
          uint2 zv = *(const uint2*)(zr + 4*j);
          f32x4 z4 = *(const f32x4*)(zbar + 64*q + 4*j);
          s += bflo(zv.x)*z4[0] + bfhi(zv.x)*z4[1] + bflo(zv.y)*z4[2] + bfhi(zv.y)*z4[3];
        }
        s += __shfl_xor(s,1); s += __shfl_xor(s,2);
        if (q == 0) gv[i] = s;
      }
    }
    __syncthreads();   // bar B: Gbar, g ready

    // ===== T1 = Gbar*P^T -> regs (wave w holds cols c=16w+l15); m1 = Q*g =====
    uint32_t t1t[16];
    {
      short8 bq[4];
#pragma unroll
      for (int k = 0; k < 4; ++k)
        bq[k] = *(const short8*)(Pl + (16*w+l15)*128 + 32*k + 8*g4);
#pragma unroll
      for (int it = 0; it < 8; ++it) {
        f32x4 d4 = {0,0,0,0};
#pragma unroll
        for (int k = 0; k < 4; ++k) {
          short8 ag = *(const short8*)(Gb + (16*it+l15)*BUFP + 32*k + 8*g4);
          d4 = MFMA16(ag, bq[k], d4);
        }
        t1t[2*it]   = pk2(d4[0], d4[1]);
        t1t[2*it+1] = pk2(d4[2], d4[3]);
      }
      // m1[d] = sum_e Q[d][e] g[e]
      {
        const int d = tid >> 2, q = lane & 3;
        float s = 0;
#pragma unroll
        for (int j = 0; j < 4; ++j) {
          short8 qv = *(const short8*)(Ql + d*128 + 32*q + 8*j);
          f32x4 g0 = *(const f32x4*)(gv + 32*q + 8*j);
          f32x4 g1 = *(const f32x4*)(gv + 32*q + 8*j + 4);
          s += bfu((uint16_t)qv[0])*g0[0] + bfu((uint16_t)qv[1])*g0[1]
             + bfu((uint16_t)qv[2])*g0[2] + bfu((uint16_t)qv[3])*g0[3]
             + bfu((uint16_t)qv[4])*g1[0] + bfu((uint16_t)qv[5])*g1[1]
             + bfu((uint16_t)qv[6])*g1[2] + bfu((uint16_t)qv[7])*g1[3];
        }
        s += __shfl_xor(s,1); s += __shfl_xor(s,2);
        if (q == 0) m1v[d] = s;
      }
    }
    __syncthreads();   // bar C: T1 reads of Gbar done; Buf reusable

    // ===== Mc[c][d] = sum_e T1t[c][e] Q[d][e]  (wave w: rows c=16w+l15) =====
    {
      F4 bfr[4];
#pragma unroll
      for (int k2 = 0; k2 < 4; ++k2) {   // e-window 32: it=2k2,2k2+1 via scratch
        *(uint2*)(scr + l15*SCRP + 4*g4)      = make_uint2(t1t[4*k2],   t1t[4*k2+1]);
        *(uint2*)(scr + l15*SCRP + 16 + 4*g4) = make_uint2(t1t[4*k2+2], t1t[4*k2+3]);
        bfr[k2].s8 = *(const short8*)(scr + l15*SCRP + 8*g4);  // same-wave RAW
      }
#pragma unroll
      for (int dt = 0; dt < 8; ++dt) {
        f32x4 d4 = {0,0,0,0};
#pragma unroll
        for (int k2 = 0; k2 < 4; ++k2) {
          short8 aq = *(const short8*)(Ql + (16*dt+l15)*128 + 32*k2 + 8*g4);
          d4 = MFMA16(aq, bfr[k2].s8, d4);
        }
        *(uint2*)(Gb + (16*w+l15)*BUFP + 16*dt + 4*g4) =
            make_uint2(pk2(d4[0],d4[1]), pk2(d4[2],d4[3]));
      }
    }
    __syncthreads();   // bar D: Mc, m1 ready

    // ===== D-main: R = Z*Mc/n + fused update (own rows); r128; r256 compute
    float r256v = 0.0f, rcv = 0.0f;
#pragma unroll
    for (int ti = 0; ti < 2; ++ti) {
      const int mb = 16*w + 128*ti;
      F4 aw[4];
      float rp = 0;
#pragma unroll
      for (int q = 0; q < 4; ++q) {      // A-frags: Z own rows from ZT columns
        uint16_t ev[8];
#pragma unroll
        for (int j = 0; j < 8; ++j) ev[j] = ZT[(32*q + 8*g4 + j)*ZTP + mb + l15];
        aw[q].u[0] = (uint32_t)ev[0] | ((uint32_t)ev[1]<<16);
        aw[q].u[1] = (uint32_t)ev[2] | ((uint32_t)ev[3]<<16);
        aw[q].u[2] = (uint32_t)ev[4] | ((uint32_t)ev[5]<<16);
        aw[q].u[3] = (uint32_t)ev[6] | ((uint32_t)ev[7]<<16);
        f32x4 m0 = *(const f32x4*)(m1v + 32*q + 8*g4);
        f32x4 m4 = *(const f32x4*)(m1v + 32*q + 8*g4 + 4);
        rp += bfu(ev[0])*m0[0] + bfu(ev[1])*m0[1] + bfu(ev[2])*m0[2] + bfu(ev[3])*m0[3]
            + bfu(ev[4])*m4[0] + bfu(ev[5])*m4[1] + bfu(ev[6])*m4[2] + bfu(ev[7])*m4[3];
      }
      rp += __shfl_xor(rp,16); rp += __shfl_xor(rp,32);
      rp *= inv_n;                       // R[mb+l15][128]
#pragma unroll
      for (int h = 0; h < 2; ++h) {      // col halves
        f32x4 racc[4];
#pragma unroll
        for (int i = 0; i < 4; ++i) racc[i] = (f32x4){0,0,0,0};
#pragma unroll
        for (int c4 = 0; c4 < 4; ++c4) {
          const int ct = 4*h + c4;
#pragma unroll
          for (int q = 0; q < 4; ++q) {
            short8 bm = *(const short8*)(Gb + (16*ct+l15)*BUFP + 32*q + 8*g4);
            racc[c4] = MFMA16(aw[q].s8, bm, racc[c4]);
          }
        }
        // fused update: z += R + acc; acc += R*gamma; re-split hi/lo
#pragma unroll
        for (int c4 = 0; c4 < 4; ++c4) {
          const int ct = 4*h + c4;
          uint16_t* zt = ZT + (16*ct+l15)*ZTP + mb + 4*g4;
          uint2 hold = *(uint2*)zt;
          const float* gp = gml + (size_t)(mb + 4*g4)*129 + 16*ct + l15;
          float R0 = racc[c4][0]*inv_n, R1 = racc[c4][1]*inv_n;
          float R2 = racc[c4][2]*inv_n, R3 = racc[c4][3]*inv_n;
          float a0 = bflo(apk[ti][2*ct]),   a1 = bfhi(apk[ti][2*ct]);
          float a2 = bflo(apk[ti][2*ct+1]), a3 = bfhi(apk[ti][2*ct+1]);
          float z0 = bflo(hold.x) + bflo(lopk[ti][2*ct])   + R0 + a0;
          float z1 = bfhi(hold.x) + bfhi(lopk[ti][2*ct])   + R1 + a1;
          float z2 = bflo(hold.y) + bflo(lopk[ti][2*ct+1]) + R2 + a2;
          float z3 = bfhi(hold.y) + bfhi(lopk[ti][2*ct+1]) + R3 + a3;
          apk[ti][2*ct]   = pk2(a0 + R0*gp[0],   a1 + R1*gp[129]);
          apk[ti][2*ct+1] = pk2(a2 + R2*gp[258], a3 + R3*gp[387]);
          uint16_t h0 = f2bf(z0), h1 = f2bf(z1), h2 = f2bf(z2), h3 = f2bf(z3);
          *(uint2*)zt = make_uint2((uint32_t)h0 | ((uint32_t)h1<<16),
                                   (uint32_t)h2 | ((uint32_t)h3<<16));
          lopk[ti][2*ct]   = pk2(z0 - bfu(h0), z1 - bfu(h1));
          lopk[ti][2*ct+1] = pk2(z2 - bfu(h2), z3 - bfu(h3));
          if (last) {
            float* zp = Zo + (size_t)(mb + 4*g4)*129 + 16*ct + l15;
            zp[0] = z0; zp[129] = z1; zp[258] = z2; zp[387] = z3;
          }
        }
      }
      if (lane < 16) {                   // col-128 master update
        const int m = mb + l15;
        float zb = zbar[m], a = acc128[m], ga = gml[m*129 + 128];
        float zn = zb + rp + a;
        zbar[m] = zn; acc128[m] = a + rp*ga;
        if (last) Zo[m*129 + 128] = zn;
      }
    }
    // r256[c] = sum_d Z[256][d]*Mc[c][d]  (4 lanes per c)
    {
      const int c = tid >> 2, q = lane & 3;
      float s = 0;
#pragma unroll
      for (int j = 0; j < 8; ++j) {
        const int d0 = 32*q + 4*j;
        uint2 mv = *(const uint2*)(Gb + c*BUFP + d0);
        s += bfu(ZT[d0*ZTP + 256])*bflo(mv.x) + bfu(ZT[(d0+1)*ZTP + 256])*bfhi(mv.x)
           + bfu(ZT[(d0+2)*ZTP + 256])*bflo(mv.y) + bfu(ZT[(d0+3)*ZTP + 256])*bfhi(mv.y);
      }
      s += __shfl_xor(s,1); s += __shfl_xor(s,2);
      r256v = s;
    }
    if (w == 0) {                        // corner: R[256][128]
      const int d0 = lane*2;
      float s = bfu(ZT[d0*ZTP + 256])*m1v[d0] + bfu(ZT[(d0+1)*ZTP + 256])*m1v[d0+1];
      s += __shfl_xor(s,1); s += __shfl_xor(s,2); s += __shfl_xor(s,4);
      s += __shfl_xor(s,8); s += __shfl_xor(s,16); s += __shfl_xor(s,32);
      rcv = s;
    }
    __syncthreads();   // bar E: row-256 reads done

    // ===== D-256: update row 256 =====
    if ((lane & 3) == 0) {
      const int c = tid >> 2;
      float R = r256v*inv_n;
      float z = z256f[c], a = acc256[c], ga = gml[256*129 + c];
      float zn = z + R + a;
      z256f[c] = zn; acc256[c] = a + R*ga; ZT[c*ZTP + 256] = f2bf(zn);
      if (last) Zo[256*129 + c] = zn;
    }
    if (w == 0 && lane == 0) {
      float R = rcv*inv_n;
      float ga = gml[256*129 + 128];
      float zn = zbar[256] + R + acc256[128];
      zbar[256] = zn; acc256[128] = acc256[128] + R*ga;
      if (last) Zo[256*129 + 128] = zn;
    }
  }
}

// allparam f32 -> bf16, both row-major: Pg[l][i][j]=P[i][j]; Qg[l][i][j]=Q[i][j].
__global__ void prep_params(const float* __restrict__ ap,
                            uint16_t* __restrict__ qg, uint16_t* __restrict__ pg)
{
  int t = blockIdx.x * 256 + threadIdx.x;   // 0..65535 = (l,i,j)
  int l = t >> 14, rem = t & 16383;
  pg[t] = f2bf(ap[(l*2 + 0)*16384 + rem]);
  qg[t] = f2bf(ap[(l*2 + 1)*16384 + rem]);
}

extern "C" void kernel_launch(void* const* d_in, const int* in_sizes, int n_in,
                              void* d_out, int out_size, void* d_ws, size_t ws_size,
                              hipStream_t stream)
{
  const float* Z  = (const float*)d_in[0];
  const float* ap = (const float*)d_in[1];
  const float* gm = (const float*)d_in[2];

  uint16_t* qg = (uint16_t*)d_ws;             // 4*128*128 bf16
  uint16_t* pg = qg + 4*128*128;              // 4*128*128 bf16 (256 KiB total)

  (void)hipFuncSetAttribute((const void*)tf_layers,
                            hipFuncAttributeMaxDynamicSharedMemorySize, LDS_TOTAL);

  prep_params<<<256, 256, 0, stream>>>(ap, qg, pg);
  tf_layers<<<512, 512, LDS_TOTAL, stream>>>(Z, gm, qg, pg, (float*)d_out);
}

// Round 9
// 267.646 us; speedup vs baseline: 2.0899x; 1.6017x over previous
//
#include <hip/hip_runtime.h>
#include <hip/hip_bf16.h>
#include <stdint.h>

// B=512, N=256, D=128, 4 layers. One block (512 thr, 8 waves) per batch.
// ALGORITHM (associativity): R = Attn*key/n = Z * (Qf * G * Pf^T) / n where
//   G = Z^T A Z = sum_{m<256} z_m z_m^T   (129x129 symmetric)
// Gbar = G[0:128,0:128], g = G[0:128,128]:
//   T1 = Gbar*P^T; M0 = Q*T1; m1 = Q*g;  R[:,c<128] = Zc*M0/n; R[:,128] = Zc*m1/n.
// STATE: master Z = bf16-hi in LDS (ZT, transposed [d][tok]) + bf16-lo residual
// in regs (own rows). acc -> GLOBAL scratch (bf16-packed uint4, coalesced
// slot*512+tid) in the first 64 KB of this block's own d_out slice: layer 0
// never reads it (poison-safe), written layer l / read layer l+1 (5 barriers
// apart -> race-free), last layer reads only, then the coalesced output phase
// overwrites the whole slice. R3-R8 lesson: >32 persistent regs => the
// immovable 128-VGPR budget spills ~500 MB to HBM and thrashes L2 (gamma
// re-fetches). Persistent now = lopk (32) only; peak live ~110.
// Phases/layer: G(SYRK) -> T1(regs) -> Mc -> D-main(+acc stream, fused update)
// -> D-256. After loop: coalesced f32 output from LDS.

using short8 = __attribute__((ext_vector_type(8))) short;
using f32x4  = __attribute__((ext_vector_type(4))) float;

#define MFMA16(A,B,C) __builtin_amdgcn_mfma_f32_16x16x32_bf16((A),(B),(C),0,0,0)

static __device__ __forceinline__ uint16_t f2bf(float f){
  union{__hip_bfloat16 h;uint16_t u;}c; c.h=__float2bfloat16(f); return c.u; }
static __device__ __forceinline__ uint32_t pk2(float lo,float hi){
  return (uint32_t)f2bf(lo) | ((uint32_t)f2bf(hi)<<16); }
static __device__ __forceinline__ float bfu(uint16_t u){ return __uint_as_float(((uint32_t)u)<<16); }
static __device__ __forceinline__ float bflo(uint32_t p){ return __uint_as_float(p<<16); }
static __device__ __forceinline__ float bfhi(uint32_t p){ return __uint_as_float(p&0xffff0000u); }

union F4 { uint32_t u[4]; short8 s8; };

// ---- LDS geometry ----
#define ZTP   280                           // ZT pitch (u16): [128][280], cols 0..256 used
#define BUFP  136                           // Gbar/Mc pitch (u16): [128][136]
#define SCRP  40                            // per-wave scratch pitch (u16): [16][40]
#define ZT_OFF   0                          // 128*280*2 = 71,680
#define BUF_OFF  71680                      // 128*136*2 = 34,816
#define SCR_OFF  106496                     // 8*16*40*2 = 10,240
#define ZBAR_OFF 116736                     // 260*4     =  1,040
#define Z256_OFF 117776                     // 128*4     =    512
#define A128_OFF 118288                     // 256*4     =  1,024
#define A256_OFF 119312                     // 132*4     =    528
#define G_OFF    119840                     // 128*4     =    512
#define M1_OFF   120352                     // 128*4     =    512
#define LDS_TOTAL 120864

__global__ __launch_bounds__(512)
__attribute__((amdgpu_waves_per_eu(2, 2)))
void tf_layers(const float* __restrict__ Zin, const float* __restrict__ gamma,
               const uint16_t* __restrict__ Qg, const uint16_t* __restrict__ Pg,
               float* __restrict__ Zout)
{
  extern __shared__ char lds[];
  uint16_t* ZT    = (uint16_t*)(lds + ZT_OFF);   // [128][ZTP]: ZT[d][tok]=bf16 Z[tok][d]
  uint16_t* Gb    = (uint16_t*)(lds + BUF_OFF);  // [128][BUFP]: Gbar, then Mc[c][d]
  float*    zbar  = (float*)(lds + ZBAR_OFF);    // [257] f32 master col 128
  float*    z256f = (float*)(lds + Z256_OFF);    // [128] f32 master row 256 (d<128)
  float*    acc128= (float*)(lds + A128_OFF);    // [256] f32 acc col 128
  float*    acc256= (float*)(lds + A256_OFF);    // [129] f32 acc row 256
  float*    gv    = (float*)(lds + G_OFF);       // [128] g = Gbar[:,128]
  float*    m1v   = (float*)(lds + M1_OFF);      // [128] m1 = Q*g

  const int tid = threadIdx.x, lane = tid & 63, w = tid >> 6;
  const int l15 = lane & 15, g4 = lane >> 4;
  const int b = blockIdx.x;
  const float inv_n = 1.0f/256.0f;

  uint16_t* scr = (uint16_t*)(lds + SCR_OFF) + w * 16 * SCRP;

  const float* Zb = Zin + (size_t)b*33153;   // 257*129
  float*       Zo = Zout + (size_t)b*33153;

  // acc scratch: 16B-aligned, inside this block's own output slice (64 KB).
  uint4* accb = (uint4*)(((uintptr_t)Zo + 15) & ~(uintptr_t)15);

  // ---- init: ZT (transposed bf16 hi), zbar, z256f, acc arrays ----
  for (int i2 = tid; i2 < 33153; i2 += 512) {
    int r = i2/129, c = i2 - r*129;
    float v = Zb[i2];
    if (c < 128) { ZT[c*ZTP + r] = f2bf(v); if (r == 256) z256f[c] = v; }
    else zbar[r] = v;
  }
  if (tid < 256) acc128[tid] = 0.0f;
  if (tid < 129) acc256[tid] = 0.0f;

  // lo residual regs for own rows (D-frag layout: row mb+4g4+rr, col 16it+l15)
  uint32_t lopk[2][16];
#pragma unroll
  for (int ti = 0; ti < 2; ++ti) {
    const int mb = 16*w + 128*ti;
#pragma unroll
    for (int it = 0; it < 8; ++it) {
      const float* zp = Zb + (size_t)(mb + 4*g4)*129 + 16*it + l15;
      float v0 = zp[0], v1 = zp[129], v2 = zp[258], v3 = zp[387];
      lopk[ti][2*it]   = pk2(v0 - bfu(f2bf(v0)), v1 - bfu(f2bf(v1)));
      lopk[ti][2*it+1] = pk2(v2 - bfu(f2bf(v2)), v3 - bfu(f2bf(v3)));
    }
  }

#pragma unroll 1
  for (int l = 0; l < 4; ++l) {
    const uint16_t* Ql  = Qg + l*16384;
    const uint16_t* Pl  = Pg + l*16384;
    const float*    gml = gamma + l*33153;
    const bool last = (l == 3);

    __syncthreads();   // bar A: ZT/zbar/z256f stable; Buf free

    // ===== G: Gbar[i][j] = sum_{m<256} Z[m][i]Z[m][j]; g[i] = sum Z[m][i]zbar[m]
    {
      f32x4 gacc[8];
#pragma unroll
      for (int jt = 0; jt < 8; ++jt) gacc[jt] = (f32x4){0,0,0,0};
#pragma unroll
      for (int mw = 0; mw < 8; ++mw) {
        short8 af = *(const short8*)(ZT + (16*w+l15)*ZTP + 32*mw + 8*g4);
#pragma unroll
        for (int jt = 0; jt < 8; ++jt) {
          short8 bf = *(const short8*)(ZT + (16*jt+l15)*ZTP + 32*mw + 8*g4);
          gacc[jt] = MFMA16(af, bf, gacc[jt]);
        }
      }
      // symmetric write: lane holds G[i=16w+4g4+rr][j=16jt+l15] -> Gb[j][i]
#pragma unroll
      for (int jt = 0; jt < 8; ++jt)
        *(uint2*)(Gb + (16*jt+l15)*BUFP + 16*w + 4*g4) =
            make_uint2(pk2(gacc[jt][0],gacc[jt][1]), pk2(gacc[jt][2],gacc[jt][3]));
      // g GEMV: i = tid>>2, 4 lanes x 64 tokens
      {
        const int i = tid >> 2, q = lane & 3;
        const uint16_t* zr = ZT + i*ZTP + 64*q;
        float s = 0;
#pragma unroll
        for (int j = 0; j < 16; ++j) {
          uint2 zv = *(const uint2*)(zr + 4*j);
          f32x4 z4 = *(const f32x4*)(zbar + 64*q + 4*j);
          s += bflo(zv.x)*z4[0] + bfhi(zv.x)*z4[1] + bflo(zv.y)*z4[2] + bfhi(zv.y)*z4[3];
        }
        s += __shfl_xor(s,1); s += __shfl_xor(s,2);
        if (q == 0) gv[i] = s;
      }
    }
    __syncthreads();   // bar B: Gbar, g ready

    // ===== T1 = Gbar*P^T -> regs (wave w holds cols c=16w+l15); m1 = Q*g =====
    uint32_t t1t[16];
    {
      short8 bq[4];
#pragma unroll
      for (int k = 0; k < 4; ++k)
        bq[k] = *(const short8*)(Pl + (16*w+l15)*128 + 32*k + 8*g4);
#pragma unroll
      for (int it = 0; it < 8; ++it) {
        f32x4 d4 = {0,0,0,0};
#pragma unroll
        for (int k = 0; k < 4; ++k) {
          short8 ag = *(const short8*)(Gb + (16*it+l15)*BUFP + 32*k + 8*g4);
          d4 = MFMA16(ag, bq[k], d4);
        }
        t1t[2*it]   = pk2(d4[0], d4[1]);
        t1t[2*it+1] = pk2(d4[2], d4[3]);
      }
      // m1[d] = sum_e Q[d][e] g[e]
      {
        const int d = tid >> 2, q = lane & 3;
        float s = 0;
#pragma unroll
        for (int j = 0; j < 4; ++j) {
          short8 qv = *(const short8*)(Ql + d*128 + 32*q + 8*j);
          f32x4 g0 = *(const f32x4*)(gv + 32*q + 8*j);
          f32x4 g1 = *(const f32x4*)(gv + 32*q + 8*j + 4);
          s += bfu((uint16_t)qv[0])*g0[0] + bfu((uint16_t)qv[1])*g0[1]
             + bfu((uint16_t)qv[2])*g0[2] + bfu((uint16_t)qv[3])*g0[3]
             + bfu((uint16_t)qv[4])*g1[0] + bfu((uint16_t)qv[5])*g1[1]
             + bfu((uint16_t)qv[6])*g1[2] + bfu((uint16_t)qv[7])*g1[3];
        }
        s += __shfl_xor(s,1); s += __shfl_xor(s,2);
        if (q == 0) m1v[d] = s;
      }
    }
    __syncthreads();   // bar C: T1 reads of Gbar done; Buf reusable

    // ===== Mc[c][d] = sum_e T1t[c][e] Q[d][e]  (wave w: rows c=16w+l15) =====
    {
      F4 bfr[4];
#pragma unroll
      for (int k2 = 0; k2 < 4; ++k2) {
        *(uint2*)(scr + l15*SCRP + 4*g4)      = make_uint2(t1t[4*k2],   t1t[4*k2+1]);
        *(uint2*)(scr + l15*SCRP + 16 + 4*g4) = make_uint2(t1t[4*k2+2], t1t[4*k2+3]);
        bfr[k2].s8 = *(const short8*)(scr + l15*SCRP + 8*g4);  // same-wave RAW
      }
#pragma unroll
      for (int dt = 0; dt < 8; ++dt) {
        f32x4 d4 = {0,0,0,0};
#pragma unroll
        for (int k2 = 0; k2 < 4; ++k2) {
          short8 aq = *(const short8*)(Ql + (16*dt+l15)*128 + 32*k2 + 8*g4);
          d4 = MFMA16(aq, bfr[k2].s8, d4);
        }
        *(uint2*)(Gb + (16*w+l15)*BUFP + 16*dt + 4*g4) =
            make_uint2(pk2(d4[0],d4[1]), pk2(d4[2],d4[3]));
      }
    }
    __syncthreads();   // bar D: Mc, m1 ready

    // ===== D-main: R = Z*Mc/n + fused update (own rows); r128; r256 =====
    float r256v = 0.0f, rcv = 0.0f;
#pragma unroll
    for (int ti = 0; ti < 2; ++ti) {
      const int mb = 16*w + 128*ti;
      F4 aw[4];
      float rp = 0;
#pragma unroll
      for (int q = 0; q < 4; ++q) {      // A-frags: Z own rows from ZT columns
        uint16_t ev[8];
#pragma unroll
        for (int j = 0; j < 8; ++j) ev[j] = ZT[(32*q + 8*g4 + j)*ZTP + mb + l15];
        aw[q].u[0] = (uint32_t)ev[0] | ((uint32_t)ev[1]<<16);
        aw[q].u[1] = (uint32_t)ev[2] | ((uint32_t)ev[3]<<16);
        aw[q].u[2] = (uint32_t)ev[4] | ((uint32_t)ev[5]<<16);
        aw[q].u[3] = (uint32_t)ev[6] | ((uint32_t)ev[7]<<16);
        f32x4 m0 = *(const f32x4*)(m1v + 32*q + 8*g4);
        f32x4 m4 = *(const f32x4*)(m1v + 32*q + 8*g4 + 4);
        rp += bfu(ev[0])*m0[0] + bfu(ev[1])*m0[1] + bfu(ev[2])*m0[2] + bfu(ev[3])*m0[3]
            + bfu(ev[4])*m4[0] + bfu(ev[5])*m4[1] + bfu(ev[6])*m4[2] + bfu(ev[7])*m4[3];
      }
      rp += __shfl_xor(rp,16); rp += __shfl_xor(rp,32);
      rp *= inv_n;                       // R[mb+l15][128]
#pragma unroll
      for (int h = 0; h < 2; ++h) {      // col halves
        f32x4 racc[4];
#pragma unroll
        for (int i = 0; i < 4; ++i) racc[i] = (f32x4){0,0,0,0};
#pragma unroll
        for (int c4 = 0; c4 < 4; ++c4) {
          const int ct = 4*h + c4;
#pragma unroll
          for (int q = 0; q < 4; ++q) {
            short8 bm = *(const short8*)(Gb + (16*ct+l15)*BUFP + 32*q + 8*g4);
            racc[c4] = MFMA16(aw[q].s8, bm, racc[c4]);
          }
        }
        // acc load (coalesced bf16-packed stream in d_out scratch)
        uint32_t ao[8];
        if (l > 0) {
          uint4 q0 = accb[(((ti*2 + h)*2 + 0) << 9) + tid];
          uint4 q1 = accb[(((ti*2 + h)*2 + 1) << 9) + tid];
          ao[0]=q0.x; ao[1]=q0.y; ao[2]=q0.z; ao[3]=q0.w;
          ao[4]=q1.x; ao[5]=q1.y; ao[6]=q1.z; ao[7]=q1.w;
        } else {
#pragma unroll
          for (int i = 0; i < 8; ++i) ao[i] = 0;
        }
        uint32_t an[8];
#pragma unroll
        for (int c4 = 0; c4 < 4; ++c4) {
          const int ct = 4*h + c4;
          uint16_t* zt = ZT + (16*ct+l15)*ZTP + mb + 4*g4;
          uint2 hold = *(uint2*)zt;
          const float* gp = gml + (size_t)(mb + 4*g4)*129 + 16*ct + l15;
          float R0 = racc[c4][0]*inv_n, R1 = racc[c4][1]*inv_n;
          float R2 = racc[c4][2]*inv_n, R3 = racc[c4][3]*inv_n;
          float a0 = bflo(ao[2*c4]),   a1 = bfhi(ao[2*c4]);
          float a2 = bflo(ao[2*c4+1]), a3 = bfhi(ao[2*c4+1]);
          float z0 = bflo(hold.x) + bflo(lopk[ti][2*ct])   + R0 + a0;
          float z1 = bfhi(hold.x) + bfhi(lopk[ti][2*ct])   + R1 + a1;
          float z2 = bflo(hold.y) + bflo(lopk[ti][2*ct+1]) + R2 + a2;
          float z3 = bfhi(hold.y) + bfhi(lopk[ti][2*ct+1]) + R3 + a3;
          an[2*c4]   = pk2(a0 + R0*gp[0],   a1 + R1*gp[129]);
          an[2*c4+1] = pk2(a2 + R2*gp[258], a3 + R3*gp[387]);
          uint16_t h0 = f2bf(z0), h1 = f2bf(z1), h2 = f2bf(z2), h3 = f2bf(z3);
          *(uint2*)zt = make_uint2((uint32_t)h0 | ((uint32_t)h1<<16),
                                   (uint32_t)h2 | ((uint32_t)h3<<16));
          lopk[ti][2*ct]   = pk2(z0 - bfu(h0), z1 - bfu(h1));
          lopk[ti][2*ct+1] = pk2(z2 - bfu(h2), z3 - bfu(h3));
        }
        if (!last) {
          accb[(((ti*2 + h)*2 + 0) << 9) + tid] = make_uint4(an[0],an[1],an[2],an[3]);
          accb[(((ti*2 + h)*2 + 1) << 9) + tid] = make_uint4(an[4],an[5],an[6],an[7]);
        }
      }
      if (lane < 16) {                   // col-128 master update (f32 in LDS)
        const int m = mb + l15;
        float zb = zbar[m], a = acc128[m], ga = gml[m*129 + 128];
        float zn = zb + rp + a;
        zbar[m] = zn; acc128[m] = a + rp*ga;
      }
    }
    // r256[c] = sum_d Z[256][d]*Mc[c][d]  (4 lanes per c)
    {
      const int c = tid >> 2, q = lane & 3;
      float s = 0;
#pragma unroll
      for (int j = 0; j < 8; ++j) {
        const int d0 = 32*q + 4*j;
        uint2 mv = *(const uint2*)(Gb + c*BUFP + d0);
        s += bfu(ZT[d0*ZTP + 256])*bflo(mv.x) + bfu(ZT[(d0+1)*ZTP + 256])*bfhi(mv.x)
           + bfu(ZT[(d0+2)*ZTP + 256])*bflo(mv.y) + bfu(ZT[(d0+3)*ZTP + 256])*bfhi(mv.y);
      }
      s += __shfl_xor(s,1); s += __shfl_xor(s,2);
      r256v = s;
    }
    if (w == 0) {                        // corner: R[256][128]
      const int d0 = lane*2;
      float s = bfu(ZT[d0*ZTP + 256])*m1v[d0] + bfu(ZT[(d0+1)*ZTP + 256])*m1v[d0+1];
      s += __shfl_xor(s,1); s += __shfl_xor(s,2); s += __shfl_xor(s,4);
      s += __shfl_xor(s,8); s += __shfl_xor(s,16); s += __shfl_xor(s,32);
      rcv = s;
    }
    __syncthreads();   // bar E: row-256 reads done

    // ===== D-256: update row 256 =====
    if ((lane & 3) == 0) {
      const int c = tid >> 2;
      float R = r256v*inv_n;
      float z = z256f[c], a = acc256[c], ga = gml[256*129 + c];
      float zn = z + R + a;
      z256f[c] = zn; acc256[c] = a + R*ga; ZT[c*ZTP + 256] = f2bf(zn);
    }
    if (w == 0 && lane == 0) {
      float R = rcv*inv_n;
      float ga = gml[256*129 + 128];
      float zn = zbar[256] + R + acc256[128];
      zbar[256] = zn; acc256[128] = acc256[128] + R*ga;
    }
  }

  // ---- coalesced f32 output from LDS (overwrites acc scratch region too) ----
  __syncthreads();
  for (int i2 = tid; i2 < 33153; i2 += 512) {
    int r = i2/129, c = i2 - r*129;
    float v;
    if (c < 128) v = (r == 256) ? z256f[c] : bfu(ZT[c*ZTP + r]);
    else         v = zbar[r];
    Zo[i2] = v;
  }
}

// allparam f32 -> bf16, both row-major: Pg[l][i][j]=P[i][j]; Qg[l][i][j]=Q[i][j].
__global__ void prep_params(const float* __restrict__ ap,
                            uint16_t* __restrict__ qg, uint16_t* __restrict__ pg)
{
  int t = blockIdx.x * 256 + threadIdx.x;   // 0..65535 = (l,i,j)
  int l = t >> 14, rem = t & 16383;
  pg[t] = f2bf(ap[(l*2 + 0)*16384 + rem]);
  qg[t] = f2bf(ap[(l*2 + 1)*16384 + rem]);
}

extern "C" void kernel_launch(void* const* d_in, const int* in_sizes, int n_in,
                              void* d_out, int out_size, void* d_ws, size_t ws_size,
                              hipStream_t stream)
{
  const float* Z  = (const float*)d_in[0];
  const float* ap = (const float*)d_in[1];
  const float* gm = (const float*)d_in[2];

  uint16_t* qg = (uint16_t*)d_ws;             // 4*128*128 bf16
  uint16_t* pg = qg + 4*128*128;              // 4*128*128 bf16 (256 KiB total)

  (void)hipFuncSetAttribute((const void*)tf_layers,
                            hipFuncAttributeMaxDynamicSharedMemorySize, LDS_TOTAL);

  prep_params<<<256, 256, 0, stream>>>(ap, qg, pg);
  tf_layers<<<512, 512, LDS_TOTAL, stream>>>(Z, gm, qg, pg, (float*)d_out);
}